// Round 4
// baseline (345.576 us; speedup 1.0000x reference)
//
#include <hip/hip_runtime.h>

typedef __bf16 bf16x8 __attribute__((ext_vector_type(8)));
typedef float  f32x4  __attribute__((ext_vector_type(4)));
typedef unsigned int u32x4 __attribute__((ext_vector_type(4)));
typedef unsigned short u16;

#define NPTS 8192      // N
#define NB   4         // B
#define KNN  16
#define ROW  132       // 3 + 128 + 1 pad
#define CF   131       // channels gathered (xyz + feat)
#define AGG_STRIDE 1064  // 1056 (=33*32 padded K) + 8 pad; *2B = 2128 B (16B mult)
#define NEG 0.1f

__device__ __forceinline__ float b2f(u16 h) {
    return __uint_as_float(((unsigned int)h) << 16);
}
__device__ __forceinline__ u16 f2bf(float f) {
    unsigned int u = __float_as_uint(f);
    unsigned int r = (u + 0x7FFFu + ((u >> 16) & 1u)) >> 16;
    return (u16)r;
}

// ---------------------------------------------------------------------------
// Pack [xyz;feat] (FP32, channel-major) into row-major bf16 rows of length 132,
// plus an exact fp32 xyz table for rel-coord computation.
__global__ __launch_bounds__(256) void pack_fcT(
    const float* __restrict__ xyz,   // [B][3][N] fp32
    const float* __restrict__ feat,  // [B][128][N] fp32
    u16* __restrict__ fcT1,          // [B*N][132] bf16 rows
    u16* __restrict__ fcT2,          // [B*N][132] (cols 0..2 and 131 here)
    float* __restrict__ xyzF)        // [B*N][4] fp32 (col 3 unused)
{
    __shared__ u16 tile[132 * 65];
    int t = threadIdx.x;
    int blk = blockIdx.x;
    int b = blk >> 7;                // / (N/64)
    int n0 = (blk & 127) << 6;       // *64
    int nn = t & 63;
    for (int c = (t >> 6); c < CF; c += 4) {
        float v;
        if (c < 3) v = xyz[(size_t)b * 3 * NPTS + (size_t)c * NPTS + n0 + nn];
        else       v = feat[(size_t)b * 128 * NPTS + (size_t)(c - 3) * NPTS + n0 + nn];
        tile[c * 65 + nn] = f2bf(v);
        if (c < 3) xyzF[((size_t)b * NPTS + n0 + nn) * 4 + c] = v;
    }
    __syncthreads();
    for (int e = t; e < 64 * ROW; e += 256) {
        int r = e / ROW;
        int c = e - r * ROW;
        u16 v = (c < CF) ? tile[c * 65 + r] : (u16)0;
        size_t row = (size_t)b * NPTS + n0 + r;
        fcT1[row * ROW + c] = v;
        if (c < 3) fcT2[row * ROW + c] = v;
        else if (c == 131) fcT2[row * ROW + c] = 0;
    }
}

// ---------------------------------------------------------------------------
// Pack fp32 weight matrix w[O][Cin] into bf16 MFMA B-fragment order:
// out[((s*T + t)*64 + lane)*8 + j] = w[t*16 + (lane&15)][s*32 + (lane>>4)*8 + j]
__global__ __launch_bounds__(256) void pack_w(
    const float* __restrict__ w, u16* __restrict__ out, int O, int Cin, int S)
{
    int T = O >> 4;
    int total = S * T * 64;
    for (int tid = blockIdx.x * blockDim.x + threadIdx.x; tid < total;
         tid += gridDim.x * blockDim.x) {
        int l = tid & 63;
        int st = tid >> 6;
        int t = st % T;
        int s = st / T;
        int o = t * 16 + (l & 15);
        int kb = s * 32 + ((l >> 4) * 8);
        #pragma unroll
        for (int j = 0; j < 8; j++) {
            int k = kb + j;
            out[(size_t)tid * 8 + j] = (k < Cin) ? f2bf(w[(size_t)o * Cin + k]) : (u16)0;
        }
    }
}

// ---------------------------------------------------------------------------
// Fused point-conv. One block = 16 points. grid = B*N/16 = 2048 blocks of 256.
// mode 0: write rows at col offset 3, stride 132 (fcT2); mode 1: stride 128 (f2)
__global__ __launch_bounds__(256) void pc_kernel(
    const u16*   __restrict__ fcT,   // [B*N][132] bf16 input rows
    const float* __restrict__ xyzF,  // [B*N][4] fp32 exact coords
    const int*   __restrict__ knn,   // [B][N][16]
    const float* __restrict__ wn_w,  // [8][3] fp32
    const float* __restrict__ wn_b,  // [8]   fp32
    const u16*   __restrict__ lwP,   // packed bf16 [33][8][64][8]
    const float* __restrict__ lin_b, // [128] fp32
    u16* __restrict__ out,
    int mode)
{
    __shared__ float w_lds[8 * 256];               // [j][k*16 + p]
    __shared__ int rb_lds[256];                    // [p][k]
    __shared__ __align__(16) u16 agg[16 * AGG_STRIDE];

    int t = threadIdx.x;
    int pt0 = blockIdx.x * 16;
    int b = pt0 >> 13;
    int n0 = pt0 & (NPTS - 1);

    // ---- phase 0: indices, rel coords (fp32 exact), weight-net ----
    {
        int p = t >> 4, k = t & 15;
        size_t rowC = (size_t)b * NPTS + n0 + p;
        int idxv = knn[rowC * KNN + k];
        int rb = b * NPTS + idxv;
        rb_lds[p * 16 + k] = rb;
        const float* cx = xyzF + rowC * 4;
        const float* nx = xyzF + (size_t)rb * 4;
        float rx = nx[0] - cx[0];
        float ry = nx[1] - cx[1];
        float rz = nx[2] - cx[2];
        #pragma unroll
        for (int j = 0; j < 8; j++) {
            float wj = wn_w[j * 3 + 0] * rx + wn_w[j * 3 + 1] * ry +
                       wn_w[j * 3 + 2] * rz + wn_b[j];
            wj = (wj < 0.0f) ? NEG * wj : wj;
            w_lds[j * 256 + k * 16 + p] = wj;
        }
        if (t < 128) {  // zero K padding (cols 1048..1055)
            int pp = t >> 3, kk = t & 7;
            agg[pp * AGG_STRIDE + 1048 + kk] = 0;
        }
    }
    __syncthreads();

    // ---- phase 1: agg[p][j*131 + c] = sum_k w[j][k] * knf[c][k] ----
    {
        int p = t >> 4, cl = t & 15;
        float acc[9][8];
        #pragma unroll
        for (int ci = 0; ci < 9; ci++)
            #pragma unroll
            for (int j = 0; j < 8; j++) acc[ci][j] = 0.0f;

        #pragma unroll
        for (int k = 0; k < 16; k++) {
            int rb = rb_lds[p * 16 + k];
            const u16* rp = fcT + (size_t)rb * ROW;
            float w8[8];
            #pragma unroll
            for (int j = 0; j < 8; j++) w8[j] = w_lds[j * 256 + k * 16 + p];
            #pragma unroll
            for (int ci = 0; ci < 8; ci++) {
                float v = b2f(rp[cl + ci * 16]);
                #pragma unroll
                for (int j = 0; j < 8; j++) acc[ci][j] += w8[j] * v;
            }
            if (cl < 3) {
                float v = b2f(rp[cl + 128]);
                #pragma unroll
                for (int j = 0; j < 8; j++) acc[8][j] += w8[j] * v;
            }
        }
        #pragma unroll
        for (int ci = 0; ci < 8; ci++) {
            int c = cl + ci * 16;
            #pragma unroll
            for (int j = 0; j < 8; j++)
                agg[p * AGG_STRIDE + j * CF + c] = f2bf(acc[ci][j]);
        }
        if (cl < 3) {
            int c = cl + 128;
            #pragma unroll
            for (int j = 0; j < 8; j++)
                agg[p * AGG_STRIDE + j * CF + c] = f2bf(acc[8][j]);
        }
    }
    __syncthreads();

    // ---- phase 2: out[16][128] = agg @ lin_w^T via MFMA ----
    {
        int wv = t >> 6, lane = t & 63;
        int m = lane & 15, quad = lane >> 4;
        int t1 = wv, t2 = wv + 4;
        f32x4 acc1 = {0.f, 0.f, 0.f, 0.f};
        f32x4 acc2 = {0.f, 0.f, 0.f, 0.f};
        for (int s = 0; s < 33; s++) {
            u32x4 av = *(const u32x4*)(agg + m * AGG_STRIDE + s * 32 + quad * 8);
            u32x4 bv1 = *(const u32x4*)(lwP + (((size_t)(s * 8 + t1) * 64 + lane) << 3));
            u32x4 bv2 = *(const u32x4*)(lwP + (((size_t)(s * 8 + t2) * 64 + lane) << 3));
            bf16x8 a  = __builtin_bit_cast(bf16x8, av);
            bf16x8 b1 = __builtin_bit_cast(bf16x8, bv1);
            bf16x8 b2 = __builtin_bit_cast(bf16x8, bv2);
            acc1 = __builtin_amdgcn_mfma_f32_16x16x32_bf16(a, b1, acc1, 0, 0, 0);
            acc2 = __builtin_amdgcn_mfma_f32_16x16x32_bf16(a, b2, acc2, 0, 0, 0);
        }
        int col = lane & 15;
        int o1 = t1 * 16 + col;
        int o2 = t2 * 16 + col;
        float bb1 = lin_b[o1];
        float bb2 = lin_b[o2];
        #pragma unroll
        for (int r = 0; r < 4; r++) {
            int prow = pt0 + quad * 4 + r;
            float v1 = acc1[r] + bb1; v1 = (v1 < 0.0f) ? NEG * v1 : v1;
            float v2 = acc2[r] + bb2; v2 = (v2 < 0.0f) ? NEG * v2 : v2;
            if (mode == 0) {
                out[(size_t)prow * ROW + 3 + o1] = f2bf(v1);
                out[(size_t)prow * ROW + 3 + o2] = f2bf(v2);
            } else {
                out[(size_t)prow * 128 + o1] = f2bf(v1);
                out[(size_t)prow * 128 + o2] = f2bf(v2);
            }
        }
    }
}

// ---------------------------------------------------------------------------
// MLP head. One block = 16 points. OUTPUT IS FP32 (d_out is float*).
__global__ __launch_bounds__(256) void mlp_kernel(
    const u16*   __restrict__ f2,    // [B*N][128] bf16
    const u16*   __restrict__ m1P,   // packed bf16 [4][8][64][8]
    const float* __restrict__ m1_b,  // [128] fp32
    const u16*   __restrict__ m2P,   // packed bf16 [4][4][64][8]
    const float* __restrict__ m2_b,  // [64] fp32
    const float* __restrict__ cl_w,  // [3][64] fp32
    const float* __restrict__ cl_b,  // [3] fp32
    float* __restrict__ dout)        // fp32 output: [B,64,N] then [B,3,N]
{
    __shared__ __align__(16) u16 h1[16 * 136];  // stride 136*2B = 272B
    __shared__ float ff[16 * 68];

    int t = threadIdx.x;
    int pt0 = blockIdx.x * 16;
    int b = pt0 >> 13;
    int n0 = pt0 & (NPTS - 1);
    int wv = t >> 6, lane = t & 63;
    int m = lane & 15, quad = lane >> 4;
    int col = lane & 15;

    // GEMM1: [16 x 128] = f2_tile @ m1^T
    {
        f32x4 acc1 = {0.f, 0.f, 0.f, 0.f};
        f32x4 acc2 = {0.f, 0.f, 0.f, 0.f};
        for (int s = 0; s < 4; s++) {
            u32x4 av = *(const u32x4*)(f2 + (size_t)(pt0 + m) * 128 + s * 32 + quad * 8);
            u32x4 bv1 = *(const u32x4*)(m1P + (((size_t)(s * 8 + wv) * 64 + lane) << 3));
            u32x4 bv2 = *(const u32x4*)(m1P + (((size_t)(s * 8 + wv + 4) * 64 + lane) << 3));
            bf16x8 a  = __builtin_bit_cast(bf16x8, av);
            bf16x8 b1 = __builtin_bit_cast(bf16x8, bv1);
            bf16x8 b2 = __builtin_bit_cast(bf16x8, bv2);
            acc1 = __builtin_amdgcn_mfma_f32_16x16x32_bf16(a, b1, acc1, 0, 0, 0);
            acc2 = __builtin_amdgcn_mfma_f32_16x16x32_bf16(a, b2, acc2, 0, 0, 0);
        }
        int o1 = wv * 16 + col, o2 = (wv + 4) * 16 + col;
        float bb1 = m1_b[o1];
        float bb2 = m1_b[o2];
        #pragma unroll
        for (int r = 0; r < 4; r++) {
            int pr = quad * 4 + r;
            float v1 = acc1[r] + bb1; v1 = (v1 < 0.0f) ? NEG * v1 : v1;
            float v2 = acc2[r] + bb2; v2 = (v2 < 0.0f) ? NEG * v2 : v2;
            h1[pr * 136 + o1] = f2bf(v1);
            h1[pr * 136 + o2] = f2bf(v2);
        }
    }
    __syncthreads();

    // GEMM2: [16 x 64] = h1 @ m2^T -> flow_feat (fp32 d_out) + ff (fp32 LDS)
    {
        f32x4 acc = {0.f, 0.f, 0.f, 0.f};
        for (int s = 0; s < 4; s++) {
            u32x4 av = *(const u32x4*)(h1 + m * 136 + s * 32 + quad * 8);
            u32x4 bv = *(const u32x4*)(m2P + (((size_t)(s * 4 + wv) * 64 + lane) << 3));
            bf16x8 a  = __builtin_bit_cast(bf16x8, av);
            bf16x8 bb = __builtin_bit_cast(bf16x8, bv);
            acc = __builtin_amdgcn_mfma_f32_16x16x32_bf16(a, bb, acc, 0, 0, 0);
        }
        int o = wv * 16 + col;
        float bb = m2_b[o];
        #pragma unroll
        for (int r = 0; r < 4; r++) {
            int pr = quad * 4 + r;
            float v = acc[r] + bb;
            v = (v < 0.0f) ? NEG * v : v;
            dout[((size_t)b * 64 + o) * NPTS + n0 + pr] = v;
            ff[pr * 68 + o] = v;
        }
    }
    __syncthreads();

    // flow = cl_w @ ff + cl_b (no activation), fp32 out
    if (t < 48) {
        int p = t & 15, oo = t >> 4;
        float a = cl_b[oo];
        #pragma unroll
        for (int i = 0; i < 64; i++)
            a += cl_w[oo * 64 + i] * ff[p * 68 + i];
        dout[(size_t)NB * 64 * NPTS + ((size_t)b * 3 + oo) * NPTS + n0 + p] = a;
    }
}

// ---------------------------------------------------------------------------
extern "C" void kernel_launch(void* const* d_in, const int* in_sizes, int n_in,
                              void* d_out, int out_size, void* d_ws, size_t ws_size,
                              hipStream_t stream) {
    const float* xyz   = (const float*)d_in[0];
    const float* feat  = (const float*)d_in[1];
    const int*   knn   = (const int*)d_in[2];
    const float* wn1_w = (const float*)d_in[3];
    const float* wn1_b = (const float*)d_in[4];
    const float* lin1w = (const float*)d_in[5];
    const float* lin1b = (const float*)d_in[6];
    const float* wn2_w = (const float*)d_in[7];
    const float* wn2_b = (const float*)d_in[8];
    const float* lin2w = (const float*)d_in[9];
    const float* lin2b = (const float*)d_in[10];
    const float* m1_w  = (const float*)d_in[11];
    const float* m1_b  = (const float*)d_in[12];
    const float* m2_w  = (const float*)d_in[13];
    const float* m2_b  = (const float*)d_in[14];
    const float* cl_w  = (const float*)d_in[15];
    const float* cl_b  = (const float*)d_in[16];
    float* out = (float*)d_out;

    char* ws = (char*)d_ws;
    const size_t BN = (size_t)NB * NPTS;
    // f2 aliases fcT1 (fcT1 dead after pc#1; pc#2 reads fcT2 only)
    u16*   fcT1 = (u16*)(ws);                      // BN*132*2 = 8,650,752
    u16*   f2   = (u16*)(ws);                      // alias
    u16*   fcT2 = (u16*)(ws + 8650752);            // 8,650,752
    float* xyzF = (float*)(ws + 17301504);         // BN*4*4 = 524,288
    u16*   lw1P = (u16*)(ws + 17825792);           // 270,336
    u16*   lw2P = (u16*)(ws + 18096128);           // 270,336
    u16*   m1P  = (u16*)(ws + 18366464);           // 32,768
    u16*   m2P  = (u16*)(ws + 18399232);           // 16,384  -> total 18,415,616

    (void)in_sizes; (void)n_in; (void)out_size; (void)ws_size;

    pack_fcT<<<dim3(NB * (NPTS / 64)), dim3(256), 0, stream>>>(xyz, feat, fcT1, fcT2, xyzF);
    pack_w<<<dim3(66), dim3(256), 0, stream>>>(lin1w, lw1P, 128, 1048, 33);
    pack_w<<<dim3(66), dim3(256), 0, stream>>>(lin2w, lw2P, 128, 1048, 33);
    pack_w<<<dim3(8),  dim3(256), 0, stream>>>(m1_w, m1P, 128, 128, 4);
    pack_w<<<dim3(4),  dim3(256), 0, stream>>>(m2_w, m2P, 64, 128, 4);

    pc_kernel<<<dim3(BN / 16), dim3(256), 0, stream>>>(
        fcT1, xyzF, knn, wn1_w, wn1_b, lw1P, lin1b, fcT2, 0);
    pc_kernel<<<dim3(BN / 16), dim3(256), 0, stream>>>(
        fcT2, xyzF, knn, wn2_w, wn2_b, lw2P, lin2b, f2, 1);

    mlp_kernel<<<dim3(BN / 16), dim3(256), 0, stream>>>(
        f2, m1P, m1_b, m2P, m2_b, cl_w, cl_b, out);
}

// Round 5
// 322.623 us; speedup vs baseline: 1.0711x; 1.0711x over previous
//
#include <hip/hip_runtime.h>

typedef __bf16 bf16x8 __attribute__((ext_vector_type(8)));
typedef float  f32x4  __attribute__((ext_vector_type(4)));
typedef float  f32x2  __attribute__((ext_vector_type(2)));
typedef unsigned int u32x4 __attribute__((ext_vector_type(4)));
typedef unsigned short u16;

#define NPTS 8192      // N
#define NB   4         // B
#define KNN  16
#define ROW  136       // 3 + 128 + 5 pad -> 272 B, 16B-aligned rows
#define CF   131       // real channels (xyz + feat)
#define JBLK 136       // k-hat block per j (permuted K), 131 data + 5 zero
#define KPAD 1088      // 8 * 136 = 34 * 32
#define NSTEP 34       // K-steps of 32
#define AGG_STRIDE 1096  // 1088 + 8; *2B = 2192 B (16B mult, banks offset 4)
#define WLDS_STRIDE 132  // per-p stride in floats: 16k*8j + 4 pad
#define NEG 0.1f

__device__ __forceinline__ float b2f(u16 h) {
    return __uint_as_float(((unsigned int)h) << 16);
}
__device__ __forceinline__ u16 f2bf(float f) {
    unsigned int u = __float_as_uint(f);
    unsigned int r = (u + 0x7FFFu + ((u >> 16) & 1u)) >> 16;
    return (u16)r;
}

// ---------------------------------------------------------------------------
// Pack [xyz;feat] (FP32, channel-major) into row-major bf16 rows of length 136,
// plus an exact fp32 xyz table for rel-coord computation.
__global__ __launch_bounds__(256) void pack_fcT(
    const float* __restrict__ xyz,   // [B][3][N] fp32
    const float* __restrict__ feat,  // [B][128][N] fp32
    u16* __restrict__ fcT1,          // [B*N][136] bf16 rows
    u16* __restrict__ fcT2,          // [B*N][136] (cols 0..2, 131..135 here)
    float* __restrict__ xyzF)        // [B*N][4] fp32 (col 3 unused)
{
    __shared__ u16 tile[CF * 65];
    int t = threadIdx.x;
    int blk = blockIdx.x;
    int b = blk >> 7;                // / (N/64)
    int n0 = (blk & 127) << 6;       // *64
    int nn = t & 63;
    for (int c = (t >> 6); c < CF; c += 4) {
        float v;
        if (c < 3) v = xyz[(size_t)b * 3 * NPTS + (size_t)c * NPTS + n0 + nn];
        else       v = feat[(size_t)b * 128 * NPTS + (size_t)(c - 3) * NPTS + n0 + nn];
        tile[c * 65 + nn] = f2bf(v);
        if (c < 3) xyzF[((size_t)b * NPTS + n0 + nn) * 4 + c] = v;
    }
    __syncthreads();
    for (int e = t; e < 64 * ROW; e += 256) {
        int r = e / ROW;
        int c = e - r * ROW;
        u16 v = (c < CF) ? tile[c * 65 + r] : (u16)0;
        size_t row = (size_t)b * NPTS + n0 + r;
        fcT1[row * ROW + c] = v;
        if (c < 3 || c >= CF) fcT2[row * ROW + c] = v;  // xyz prefix + zero pad
    }
}

// ---------------------------------------------------------------------------
// Pack fp32 weight matrix into bf16 MFMA B-fragment order over k-hat.
// remap=1: k-hat = jj*JBLK + cc maps to original k = jj*131 + cc (cc<131), else 0.
// remap=0: k-hat = k directly (dense Cin).
__global__ __launch_bounds__(256) void pack_w(
    const float* __restrict__ w, u16* __restrict__ out, int O, int Cin, int S,
    int remap)
{
    int T = O >> 4;
    int total = S * T * 64;
    for (int tid = blockIdx.x * blockDim.x + threadIdx.x; tid < total;
         tid += gridDim.x * blockDim.x) {
        int l = tid & 63;
        int st = tid >> 6;
        int t = st % T;
        int s = st / T;
        int o = t * 16 + (l & 15);
        int kb = s * 32 + ((l >> 4) * 8);
        #pragma unroll
        for (int j = 0; j < 8; j++) {
            int kh = kb + j;
            u16 v = 0;
            if (remap) {
                int jj = kh / JBLK, cc = kh - jj * JBLK;
                if (cc < CF) v = f2bf(w[(size_t)o * Cin + jj * CF + cc]);
            } else {
                if (kh < Cin) v = f2bf(w[(size_t)o * Cin + kh]);
            }
            out[(size_t)tid * 8 + j] = v;
        }
    }
}

// ---------------------------------------------------------------------------
// Fused point-conv. One block = 16 points. grid = B*N/16 = 2048 blocks of 256.
// mode 0: write rows at col offset 3, stride 136 (fcT2); mode 1: stride 128 (f2)
__global__ __launch_bounds__(256) void pc_kernel(
    const u16*   __restrict__ fcT,   // [B*N][136] bf16 input rows
    const float* __restrict__ xyzF,  // [B*N][4] fp32 exact coords
    const int*   __restrict__ knn,   // [B][N][16]
    const float* __restrict__ wn_w,  // [8][3] fp32
    const float* __restrict__ wn_b,  // [8]   fp32
    const u16*   __restrict__ lwP,   // packed bf16 [34][8][64][8] over k-hat
    const float* __restrict__ lin_b, // [128] fp32
    u16* __restrict__ out,
    int mode)
{
    __shared__ __align__(16) float w_lds[16 * WLDS_STRIDE]; // [p][k*8 + j]
    __shared__ int rb_lds[256];                             // [p][k]
    __shared__ __align__(16) u16 agg[16 * AGG_STRIDE];      // [p][k-hat]

    int t = threadIdx.x;
    int pt0 = blockIdx.x * 16;
    int b = pt0 >> 13;
    int n0 = pt0 & (NPTS - 1);

    // ---- phase 0: indices, rel coords (fp32 exact), weight-net ----
    {
        int p = t >> 4, k = t & 15;
        size_t rowC = (size_t)b * NPTS + n0 + p;
        int idxv = knn[rowC * KNN + k];
        int rb = b * NPTS + idxv;
        rb_lds[p * 16 + k] = rb;
        const float* cx = xyzF + rowC * 4;
        const float* nx = xyzF + (size_t)rb * 4;
        float rx = nx[0] - cx[0];
        float ry = nx[1] - cx[1];
        float rz = nx[2] - cx[2];
        float wj[8];
        #pragma unroll
        for (int j = 0; j < 8; j++) {
            float v = wn_w[j * 3 + 0] * rx + wn_w[j * 3 + 1] * ry +
                      wn_w[j * 3 + 2] * rz + wn_b[j];
            wj[j] = (v < 0.0f) ? NEG * v : v;
        }
        float* wp = w_lds + p * WLDS_STRIDE + k * 8;
        *(f32x4*)(wp)     = (f32x4){wj[0], wj[1], wj[2], wj[3]};
        *(f32x4*)(wp + 4) = (f32x4){wj[4], wj[5], wj[6], wj[7]};
        // zero the k-hat pad slots c=131..135 for all (p, j): 16*8*5 = 640
        for (int e = t; e < 640; e += 256) {
            int pp = e / 40, rem = e - pp * 40;
            int jj = rem / 5, cc = CF + (rem - jj * 5);
            agg[pp * AGG_STRIDE + jj * JBLK + cc] = 0;
        }
    }
    __syncthreads();

    // ---- phase 1: agg[p][j*136 + c] = sum_k w[j][k] * knf[c][k] ----
    {
        int p = t >> 4, cl = t & 15;
        f32x2 acc[4][8];          // channels cl*8 + {0..7} as 4 float2
        float acct[8];            // tail channel 128+cl (cl<3)
        #pragma unroll
        for (int i = 0; i < 4; i++)
            #pragma unroll
            for (int j = 0; j < 8; j++) acc[i][j] = (f32x2){0.f, 0.f};
        #pragma unroll
        for (int j = 0; j < 8; j++) acct[j] = 0.f;

        #pragma unroll
        for (int k = 0; k < 16; k++) {
            int rb = rb_lds[p * 16 + k];
            const u16* rp = fcT + (size_t)rb * ROW;
            u32x4 rv = *(const u32x4*)(rp + cl * 8);
            float tl = (cl < 3) ? b2f(rp[128 + cl]) : 0.0f;
            f32x2 v[4];
            #pragma unroll
            for (int i = 0; i < 4; i++) {
                unsigned int u = rv[i];
                v[i] = (f32x2){__uint_as_float(u << 16),
                               __uint_as_float(u & 0xFFFF0000u)};
            }
            const float* wp = w_lds + p * WLDS_STRIDE + k * 8;  // broadcast
            #pragma unroll
            for (int j = 0; j < 8; j++) {
                float w = wp[j];
                f32x2 w2 = (f32x2){w, w};
                #pragma unroll
                for (int i = 0; i < 4; i++) acc[i][j] += v[i] * w2;
                acct[j] += tl * w;
            }
        }
        #pragma unroll
        for (int j = 0; j < 8; j++) {
            unsigned int o[4];
            #pragma unroll
            for (int i = 0; i < 4; i++) {
                unsigned int lo = f2bf(acc[i][j].x);
                unsigned int hi = f2bf(acc[i][j].y);
                o[i] = lo | (hi << 16);
            }
            *(u32x4*)(agg + p * AGG_STRIDE + j * JBLK + cl * 8) =
                (u32x4){o[0], o[1], o[2], o[3]};
        }
        if (cl < 3) {
            #pragma unroll
            for (int j = 0; j < 8; j++)
                agg[p * AGG_STRIDE + j * JBLK + 128 + cl] = f2bf(acct[j]);
        }
    }
    __syncthreads();

    // ---- phase 2: out[16][128] = agg @ lin_w^T via MFMA (k-hat order) ----
    {
        int wv = t >> 6, lane = t & 63;
        int m = lane & 15, quad = lane >> 4;
        int t1 = wv, t2 = wv + 4;
        f32x4 acc1 = {0.f, 0.f, 0.f, 0.f};
        f32x4 acc2 = {0.f, 0.f, 0.f, 0.f};
        for (int s = 0; s < NSTEP; s++) {
            u32x4 av = *(const u32x4*)(agg + m * AGG_STRIDE + s * 32 + quad * 8);
            u32x4 bv1 = *(const u32x4*)(lwP + (((size_t)(s * 8 + t1) * 64 + lane) << 3));
            u32x4 bv2 = *(const u32x4*)(lwP + (((size_t)(s * 8 + t2) * 64 + lane) << 3));
            bf16x8 a  = __builtin_bit_cast(bf16x8, av);
            bf16x8 b1 = __builtin_bit_cast(bf16x8, bv1);
            bf16x8 b2 = __builtin_bit_cast(bf16x8, bv2);
            acc1 = __builtin_amdgcn_mfma_f32_16x16x32_bf16(a, b1, acc1, 0, 0, 0);
            acc2 = __builtin_amdgcn_mfma_f32_16x16x32_bf16(a, b2, acc2, 0, 0, 0);
        }
        int col = lane & 15;
        int o1 = t1 * 16 + col;
        int o2 = t2 * 16 + col;
        float bb1 = lin_b[o1];
        float bb2 = lin_b[o2];
        #pragma unroll
        for (int r = 0; r < 4; r++) {
            int prow = pt0 + quad * 4 + r;
            float v1 = acc1[r] + bb1; v1 = (v1 < 0.0f) ? NEG * v1 : v1;
            float v2 = acc2[r] + bb2; v2 = (v2 < 0.0f) ? NEG * v2 : v2;
            if (mode == 0) {
                out[(size_t)prow * ROW + 3 + o1] = f2bf(v1);
                out[(size_t)prow * ROW + 3 + o2] = f2bf(v2);
            } else {
                out[(size_t)prow * 128 + o1] = f2bf(v1);
                out[(size_t)prow * 128 + o2] = f2bf(v2);
            }
        }
    }
}

// ---------------------------------------------------------------------------
// MLP head. One block = 16 points. OUTPUT IS FP32 (d_out is float*).
__global__ __launch_bounds__(256) void mlp_kernel(
    const u16*   __restrict__ f2,    // [B*N][128] bf16
    const u16*   __restrict__ m1P,   // packed bf16 [4][8][64][8]
    const float* __restrict__ m1_b,  // [128] fp32
    const u16*   __restrict__ m2P,   // packed bf16 [4][4][64][8]
    const float* __restrict__ m2_b,  // [64] fp32
    const float* __restrict__ cl_w,  // [3][64] fp32
    const float* __restrict__ cl_b,  // [3] fp32
    float* __restrict__ dout)        // fp32 output: [B,64,N] then [B,3,N]
{
    __shared__ __align__(16) u16 h1[16 * 136];  // stride 136*2B = 272B
    __shared__ float ff[16 * 68];

    int t = threadIdx.x;
    int pt0 = blockIdx.x * 16;
    int b = pt0 >> 13;
    int n0 = pt0 & (NPTS - 1);
    int wv = t >> 6, lane = t & 63;
    int m = lane & 15, quad = lane >> 4;
    int col = lane & 15;

    // GEMM1: [16 x 128] = f2_tile @ m1^T
    {
        f32x4 acc1 = {0.f, 0.f, 0.f, 0.f};
        f32x4 acc2 = {0.f, 0.f, 0.f, 0.f};
        for (int s = 0; s < 4; s++) {
            u32x4 av = *(const u32x4*)(f2 + (size_t)(pt0 + m) * 128 + s * 32 + quad * 8);
            u32x4 bv1 = *(const u32x4*)(m1P + (((size_t)(s * 8 + wv) * 64 + lane) << 3));
            u32x4 bv2 = *(const u32x4*)(m1P + (((size_t)(s * 8 + wv + 4) * 64 + lane) << 3));
            bf16x8 a  = __builtin_bit_cast(bf16x8, av);
            bf16x8 b1 = __builtin_bit_cast(bf16x8, bv1);
            bf16x8 b2 = __builtin_bit_cast(bf16x8, bv2);
            acc1 = __builtin_amdgcn_mfma_f32_16x16x32_bf16(a, b1, acc1, 0, 0, 0);
            acc2 = __builtin_amdgcn_mfma_f32_16x16x32_bf16(a, b2, acc2, 0, 0, 0);
        }
        int o1 = wv * 16 + col, o2 = (wv + 4) * 16 + col;
        float bb1 = m1_b[o1];
        float bb2 = m1_b[o2];
        #pragma unroll
        for (int r = 0; r < 4; r++) {
            int pr = quad * 4 + r;
            float v1 = acc1[r] + bb1; v1 = (v1 < 0.0f) ? NEG * v1 : v1;
            float v2 = acc2[r] + bb2; v2 = (v2 < 0.0f) ? NEG * v2 : v2;
            h1[pr * 136 + o1] = f2bf(v1);
            h1[pr * 136 + o2] = f2bf(v2);
        }
    }
    __syncthreads();

    // GEMM2: [16 x 64] = h1 @ m2^T -> flow_feat (fp32 d_out) + ff (fp32 LDS)
    {
        f32x4 acc = {0.f, 0.f, 0.f, 0.f};
        for (int s = 0; s < 4; s++) {
            u32x4 av = *(const u32x4*)(h1 + m * 136 + s * 32 + quad * 8);
            u32x4 bv = *(const u32x4*)(m2P + (((size_t)(s * 4 + wv) * 64 + lane) << 3));
            bf16x8 a  = __builtin_bit_cast(bf16x8, av);
            bf16x8 bb = __builtin_bit_cast(bf16x8, bv);
            acc = __builtin_amdgcn_mfma_f32_16x16x32_bf16(a, bb, acc, 0, 0, 0);
        }
        int o = wv * 16 + col;
        float bb = m2_b[o];
        #pragma unroll
        for (int r = 0; r < 4; r++) {
            int pr = quad * 4 + r;
            float v = acc[r] + bb;
            v = (v < 0.0f) ? NEG * v : v;
            dout[((size_t)b * 64 + o) * NPTS + n0 + pr] = v;
            ff[pr * 68 + o] = v;
        }
    }
    __syncthreads();

    // flow = cl_w @ ff + cl_b (no activation), fp32 out
    if (t < 48) {
        int p = t & 15, oo = t >> 4;
        float a = cl_b[oo];
        #pragma unroll
        for (int i = 0; i < 64; i++)
            a += cl_w[oo * 64 + i] * ff[p * 68 + i];
        dout[(size_t)NB * 64 * NPTS + ((size_t)b * 3 + oo) * NPTS + n0 + p] = a;
    }
}

// ---------------------------------------------------------------------------
extern "C" void kernel_launch(void* const* d_in, const int* in_sizes, int n_in,
                              void* d_out, int out_size, void* d_ws, size_t ws_size,
                              hipStream_t stream) {
    const float* xyz   = (const float*)d_in[0];
    const float* feat  = (const float*)d_in[1];
    const int*   knn   = (const int*)d_in[2];
    const float* wn1_w = (const float*)d_in[3];
    const float* wn1_b = (const float*)d_in[4];
    const float* lin1w = (const float*)d_in[5];
    const float* lin1b = (const float*)d_in[6];
    const float* wn2_w = (const float*)d_in[7];
    const float* wn2_b = (const float*)d_in[8];
    const float* lin2w = (const float*)d_in[9];
    const float* lin2b = (const float*)d_in[10];
    const float* m1_w  = (const float*)d_in[11];
    const float* m1_b  = (const float*)d_in[12];
    const float* m2_w  = (const float*)d_in[13];
    const float* m2_b  = (const float*)d_in[14];
    const float* cl_w  = (const float*)d_in[15];
    const float* cl_b  = (const float*)d_in[16];
    float* out = (float*)d_out;

    char* ws = (char*)d_ws;
    const size_t BN = (size_t)NB * NPTS;
    // f2 aliases fcT1 (fcT1 dead after pc#1; pc#2 reads fcT2 only)
    u16*   fcT1 = (u16*)(ws);                      // BN*136*2 = 8,912,896
    u16*   f2   = (u16*)(ws);                      // alias (BN*128*2)
    u16*   fcT2 = (u16*)(ws + 8912896);            // 8,912,896
    float* xyzF = (float*)(ws + 17825792);         // BN*4*4 = 524,288
    u16*   lw1P = (u16*)(ws + 18350080);           // 34*8*512*2 = 278,528
    u16*   lw2P = (u16*)(ws + 18628608);           // 278,528
    u16*   m1P  = (u16*)(ws + 18907136);           // 32,768
    u16*   m2P  = (u16*)(ws + 18939904);           // 16,384 -> total 18,956,288

    (void)in_sizes; (void)n_in; (void)out_size; (void)ws_size;

    pack_fcT<<<dim3(NB * (NPTS / 64)), dim3(256), 0, stream>>>(xyz, feat, fcT1, fcT2, xyzF);
    pack_w<<<dim3(68), dim3(256), 0, stream>>>(lin1w, lw1P, 128, 1048, NSTEP, 1);
    pack_w<<<dim3(68), dim3(256), 0, stream>>>(lin2w, lw2P, 128, 1048, NSTEP, 1);
    pack_w<<<dim3(8),  dim3(256), 0, stream>>>(m1_w, m1P, 128, 128, 4, 0);
    pack_w<<<dim3(4),  dim3(256), 0, stream>>>(m2_w, m2P, 64, 128, 4, 0);

    pc_kernel<<<dim3(BN / 16), dim3(256), 0, stream>>>(
        fcT1, xyzF, knn, wn1_w, wn1_b, lw1P, lin1b, fcT2, 0);
    pc_kernel<<<dim3(BN / 16), dim3(256), 0, stream>>>(
        fcT2, xyzF, knn, wn2_w, wn2_b, lw2P, lin2b, f2, 1);

    mlp_kernel<<<dim3(BN / 16), dim3(256), 0, stream>>>(
        f2, m1P, m1_b, m2P, m2_b, cl_w, cl_b, out);
}

// Round 6
// 277.683 us; speedup vs baseline: 1.2445x; 1.1618x over previous
//
#include <hip/hip_runtime.h>

typedef __bf16 bf16x8 __attribute__((ext_vector_type(8)));
typedef float  f32x4  __attribute__((ext_vector_type(4)));
typedef float  f32x2  __attribute__((ext_vector_type(2)));
typedef unsigned int u32x4 __attribute__((ext_vector_type(4)));
typedef unsigned short u16;

#define NPTS 8192      // N
#define NB   4         // B
#define KNN  16
#define ROW  136       // 3 + 128 + 5 pad u16 -> 272 B rows, 16B-aligned
#define CF   131       // real channels (xyz + feat)
#define JBLK 136       // k-hat block per j (permuted K), 131 data + 5 zero
#define KPAD 1088      // 8 * 136 = 34 * 32
#define NSTEP 34       // K-steps of 32
#define AGG_STRIDE 1096  // u16 units; 2192 B per point
#define RBST 144       // rowbuf row stride u16 (288 B = 18*16)
#define WLDS_STRIDE 132  // per-p stride in floats
#define NEG 0.1f

__device__ __forceinline__ float b2f(u16 h) {
    return __uint_as_float(((unsigned int)h) << 16);
}
__device__ __forceinline__ u16 f2bf(float f) {
    unsigned int u = __float_as_uint(f);
    unsigned int r = (u + 0x7FFFu + ((u >> 16) & 1u)) >> 16;
    return (u16)r;
}
// async global->LDS DMA, 16B per lane; LDS side must be base + lane*16
__device__ __forceinline__ void dma16(const u16* g, u16* l) {
    __builtin_amdgcn_global_load_lds(
        (const __attribute__((address_space(1))) void*)g,
        (__attribute__((address_space(3))) void*)l, 16, 0, 0);
}

// ---------------------------------------------------------------------------
// Pack [xyz;feat] (FP32, channel-major) into row-major bf16 rows of length 136,
// plus an exact fp32 xyz table for rel-coord computation.
__global__ __launch_bounds__(256) void pack_fcT(
    const float* __restrict__ xyz,   // [B][3][N] fp32
    const float* __restrict__ feat,  // [B][128][N] fp32
    u16* __restrict__ fcT1,          // [B*N][136] bf16 rows
    u16* __restrict__ fcT2,          // [B*N][136] (cols 0..2, 131..135 here)
    float* __restrict__ xyzF)        // [B*N][4] fp32 (col 3 unused)
{
    __shared__ u16 tile[CF * 65];
    int t = threadIdx.x;
    int blk = blockIdx.x;
    int b = blk >> 7;                // / (N/64)
    int n0 = (blk & 127) << 6;       // *64
    int nn = t & 63;
    for (int c = (t >> 6); c < CF; c += 4) {
        float v;
        if (c < 3) v = xyz[(size_t)b * 3 * NPTS + (size_t)c * NPTS + n0 + nn];
        else       v = feat[(size_t)b * 128 * NPTS + (size_t)(c - 3) * NPTS + n0 + nn];
        tile[c * 65 + nn] = f2bf(v);
        if (c < 3) xyzF[((size_t)b * NPTS + n0 + nn) * 4 + c] = v;
    }
    __syncthreads();
    for (int e = t; e < 64 * ROW; e += 256) {
        int r = e / ROW;
        int c = e - r * ROW;
        u16 v = (c < CF) ? tile[c * 65 + r] : (u16)0;
        size_t row = (size_t)b * NPTS + n0 + r;
        fcT1[row * ROW + c] = v;
        if (c < 3 || c >= CF) fcT2[row * ROW + c] = v;  // xyz prefix + zero pad
    }
}

// ---------------------------------------------------------------------------
// Pack fp32 weight matrix into bf16 MFMA B-fragment order over k-hat.
// remap=1: k-hat = jj*JBLK + cc maps to original k = jj*131 + cc (cc<131), else 0.
__global__ __launch_bounds__(256) void pack_w(
    const float* __restrict__ w, u16* __restrict__ out, int O, int Cin, int S,
    int remap)
{
    int T = O >> 4;
    int total = S * T * 64;
    for (int tid = blockIdx.x * blockDim.x + threadIdx.x; tid < total;
         tid += gridDim.x * blockDim.x) {
        int l = tid & 63;
        int st = tid >> 6;
        int t = st % T;
        int s = st / T;
        int o = t * 16 + (l & 15);
        int kb = s * 32 + ((l >> 4) * 8);
        #pragma unroll
        for (int j = 0; j < 8; j++) {
            int kh = kb + j;
            u16 v = 0;
            if (remap) {
                int jj = kh / JBLK, cc = kh - jj * JBLK;
                if (cc < CF) v = f2bf(w[(size_t)o * Cin + jj * CF + cc]);
            } else {
                if (kh < Cin) v = f2bf(w[(size_t)o * Cin + kh]);
            }
            out[(size_t)tid * 8 + j] = v;
        }
    }
}

// ---------------------------------------------------------------------------
// Fused point-conv. One block = 16 points. grid = B*N/16 = 2048 blocks of 256.
// Neighbor rows staged via async global_load_lds in two 8-k chunks; einsum
// reads LDS; agg tile aliases the rowbuf; MFMA GEMM vs packed lin_w.
__global__ __launch_bounds__(256) void pc_kernel(
    const u16*   __restrict__ fcT,   // [B*N][136] bf16 input rows
    const float* __restrict__ xyzF,  // [B*N][4] fp32 exact coords
    const int*   __restrict__ knn,   // [B][N][16]
    const float* __restrict__ wn_w,  // [8][3] fp32
    const float* __restrict__ wn_b,  // [8]   fp32
    const u16*   __restrict__ lwP,   // packed bf16 [34][8][64][8] over k-hat
    const float* __restrict__ lin_b, // [128] fp32
    u16* __restrict__ out,
    int mode)
{
    // rowbuf: 128 rows x 288B = 36864 B;  agg: 16 x 2192 B = 35072 B (alias)
    __shared__ __align__(16) u16 rowagg[18432];
    __shared__ __align__(16) float w_lds[16 * WLDS_STRIDE]; // [p][k*8 + j]
    __shared__ int rb_lds[256];                             // [p][k]

    int t = threadIdx.x;
    int wv = t >> 6, lane = t & 63;
    int pt0 = blockIdx.x * 16;
    int b = pt0 >> 13;
    int n0 = pt0 & (NPTS - 1);

    // ---- P0: indices, rel coords (fp32 exact), weight-net ----
    {
        int p = t >> 4, k = t & 15;
        size_t rowC = (size_t)b * NPTS + n0 + p;
        int idxv = knn[rowC * KNN + k];
        int rb = b * NPTS + idxv;
        rb_lds[p * 16 + k] = rb;
        const float* cx = xyzF + rowC * 4;
        const float* nx = xyzF + (size_t)rb * 4;
        float rx = nx[0] - cx[0];
        float ry = nx[1] - cx[1];
        float rz = nx[2] - cx[2];
        float wj[8];
        #pragma unroll
        for (int j = 0; j < 8; j++) {
            float v = wn_w[j * 3 + 0] * rx + wn_w[j * 3 + 1] * ry +
                      wn_w[j * 3 + 2] * rz + wn_b[j];
            wj[j] = (v < 0.0f) ? NEG * v : v;
        }
        float* wp = w_lds + p * WLDS_STRIDE + k * 8;
        *(f32x4*)(wp)     = (f32x4){wj[0], wj[1], wj[2], wj[3]};
        *(f32x4*)(wp + 4) = (f32x4){wj[4], wj[5], wj[6], wj[7]};
    }
    __syncthreads();

    int p = t >> 4, cl = t & 15;
    f32x2 acc[4][8];          // channels cl*8 + {0..7} as 4 float2
    float acct[8];            // tail channel 128+cl (cl<3)
    #pragma unroll
    for (int i = 0; i < 4; i++)
        #pragma unroll
        for (int j = 0; j < 8; j++) acc[i][j] = (f32x2){0.f, 0.f};
    #pragma unroll
    for (int j = 0; j < 8; j++) acct[j] = 0.f;

    #pragma unroll
    for (int ch = 0; ch < 2; ch++) {
        // ---- DMA chunk: stage rows (p, ch*8+kk) -> rowbuf, 288B stride ----
        {
            #pragma unroll
            for (int i = 0; i < 9; i++) {
                unsigned q = wv * 576 + i * 64 + lane;   // 16B-unit offset
                unsigned row = q / 18;                   // 0..127
                unsigned rem16 = q - row * 18;           // 0..17
                int pp = row >> 3, kk = row & 7;
                int rb = rb_lds[pp * 16 + ch * 8 + kk];
                dma16(fcT + (size_t)rb * ROW + rem16 * 8, rowagg + q * 8);
            }
        }
        __syncthreads();   // drains vmcnt -> rowbuf ready

        // ---- einsum chunk: acc += w[j][k] * knf[c][k] from LDS ----
        #pragma unroll
        for (int kk = 0; kk < 8; kk++) {
            const u16* rp = rowagg + (p * 8 + kk) * RBST;
            u32x4 rv = *(const u32x4*)(rp + cl * 8);
            float tl = (cl < 3) ? b2f(rp[128 + cl]) : 0.0f;
            f32x2 v[4];
            #pragma unroll
            for (int i = 0; i < 4; i++) {
                unsigned int u = rv[i];
                v[i] = (f32x2){__uint_as_float(u << 16),
                               __uint_as_float(u & 0xFFFF0000u)};
            }
            const float* wp = w_lds + p * WLDS_STRIDE + (ch * 8 + kk) * 8;
            #pragma unroll
            for (int j = 0; j < 8; j++) {
                float w = wp[j];
                f32x2 w2 = (f32x2){w, w};
                #pragma unroll
                for (int i = 0; i < 4; i++) acc[i][j] += v[i] * w2;
                acct[j] += tl * w;
            }
        }
        __syncthreads();   // all reads done before rowbuf reuse / agg write
    }

    // ---- agg write (aliases rowbuf; all rowbuf reads complete) ----
    {
        #pragma unroll
        for (int j = 0; j < 8; j++) {
            unsigned int o[4];
            #pragma unroll
            for (int i = 0; i < 4; i++) {
                unsigned int lo = f2bf(acc[i][j].x);
                unsigned int hi = f2bf(acc[i][j].y);
                o[i] = lo | (hi << 16);
            }
            *(u32x4*)(rowagg + p * AGG_STRIDE + j * JBLK + cl * 8) =
                (u32x4){o[0], o[1], o[2], o[3]};
        }
        if (cl < 3) {
            #pragma unroll
            for (int j = 0; j < 8; j++)
                rowagg[p * AGG_STRIDE + j * JBLK + 128 + cl] = f2bf(acct[j]);
        }
        if (cl < 5) {  // zero k-hat pad slots c = 131..135
            #pragma unroll
            for (int j = 0; j < 8; j++)
                rowagg[p * AGG_STRIDE + j * JBLK + CF + cl] = 0;
        }
    }
    __syncthreads();

    // ---- phase 2: out[16][128] = agg @ lin_w^T via MFMA (k-hat order) ----
    {
        int m = lane & 15, quad = lane >> 4;
        int t1 = wv, t2 = wv + 4;
        f32x4 acc1 = {0.f, 0.f, 0.f, 0.f};
        f32x4 acc2 = {0.f, 0.f, 0.f, 0.f};
        for (int s = 0; s < NSTEP; s++) {
            u32x4 av = *(const u32x4*)(rowagg + m * AGG_STRIDE + s * 32 + quad * 8);
            u32x4 bv1 = *(const u32x4*)(lwP + (((size_t)(s * 8 + t1) * 64 + lane) << 3));
            u32x4 bv2 = *(const u32x4*)(lwP + (((size_t)(s * 8 + t2) * 64 + lane) << 3));
            bf16x8 a  = __builtin_bit_cast(bf16x8, av);
            bf16x8 b1 = __builtin_bit_cast(bf16x8, bv1);
            bf16x8 b2 = __builtin_bit_cast(bf16x8, bv2);
            acc1 = __builtin_amdgcn_mfma_f32_16x16x32_bf16(a, b1, acc1, 0, 0, 0);
            acc2 = __builtin_amdgcn_mfma_f32_16x16x32_bf16(a, b2, acc2, 0, 0, 0);
        }
        int col = lane & 15;
        int o1 = t1 * 16 + col;
        int o2 = t2 * 16 + col;
        float bb1 = lin_b[o1];
        float bb2 = lin_b[o2];
        #pragma unroll
        for (int r = 0; r < 4; r++) {
            int prow = pt0 + quad * 4 + r;
            float v1 = acc1[r] + bb1; v1 = (v1 < 0.0f) ? NEG * v1 : v1;
            float v2 = acc2[r] + bb2; v2 = (v2 < 0.0f) ? NEG * v2 : v2;
            if (mode == 0) {
                out[(size_t)prow * ROW + 3 + o1] = f2bf(v1);
                out[(size_t)prow * ROW + 3 + o2] = f2bf(v2);
            } else {
                out[(size_t)prow * 128 + o1] = f2bf(v1);
                out[(size_t)prow * 128 + o2] = f2bf(v2);
            }
        }
    }
}

// ---------------------------------------------------------------------------
// MLP head. One block = 16 points. OUTPUT IS FP32 (d_out is float*).
__global__ __launch_bounds__(256) void mlp_kernel(
    const u16*   __restrict__ f2,    // [B*N][128] bf16
    const u16*   __restrict__ m1P,   // packed bf16 [4][8][64][8]
    const float* __restrict__ m1_b,  // [128] fp32
    const u16*   __restrict__ m2P,   // packed bf16 [4][4][64][8]
    const float* __restrict__ m2_b,  // [64] fp32
    const float* __restrict__ cl_w,  // [3][64] fp32
    const float* __restrict__ cl_b,  // [3] fp32
    float* __restrict__ dout)        // fp32 output: [B,64,N] then [B,3,N]
{
    __shared__ __align__(16) u16 h1[16 * 136];  // stride 136*2B = 272B
    __shared__ float ff[16 * 68];

    int t = threadIdx.x;
    int pt0 = blockIdx.x * 16;
    int b = pt0 >> 13;
    int n0 = pt0 & (NPTS - 1);
    int wv = t >> 6, lane = t & 63;
    int m = lane & 15, quad = lane >> 4;
    int col = lane & 15;

    // GEMM1: [16 x 128] = f2_tile @ m1^T
    {
        f32x4 acc1 = {0.f, 0.f, 0.f, 0.f};
        f32x4 acc2 = {0.f, 0.f, 0.f, 0.f};
        for (int s = 0; s < 4; s++) {
            u32x4 av = *(const u32x4*)(f2 + (size_t)(pt0 + m) * 128 + s * 32 + quad * 8);
            u32x4 bv1 = *(const u32x4*)(m1P + (((size_t)(s * 8 + wv) * 64 + lane) << 3));
            u32x4 bv2 = *(const u32x4*)(m1P + (((size_t)(s * 8 + wv + 4) * 64 + lane) << 3));
            bf16x8 a  = __builtin_bit_cast(bf16x8, av);
            bf16x8 b1 = __builtin_bit_cast(bf16x8, bv1);
            bf16x8 b2 = __builtin_bit_cast(bf16x8, bv2);
            acc1 = __builtin_amdgcn_mfma_f32_16x16x32_bf16(a, b1, acc1, 0, 0, 0);
            acc2 = __builtin_amdgcn_mfma_f32_16x16x32_bf16(a, b2, acc2, 0, 0, 0);
        }
        int o1 = wv * 16 + col, o2 = (wv + 4) * 16 + col;
        float bb1 = m1_b[o1];
        float bb2 = m1_b[o2];
        #pragma unroll
        for (int r = 0; r < 4; r++) {
            int pr = quad * 4 + r;
            float v1 = acc1[r] + bb1; v1 = (v1 < 0.0f) ? NEG * v1 : v1;
            float v2 = acc2[r] + bb2; v2 = (v2 < 0.0f) ? NEG * v2 : v2;
            h1[pr * 136 + o1] = f2bf(v1);
            h1[pr * 136 + o2] = f2bf(v2);
        }
    }
    __syncthreads();

    // GEMM2: [16 x 64] = h1 @ m2^T -> flow_feat (fp32 d_out) + ff (fp32 LDS)
    {
        f32x4 acc = {0.f, 0.f, 0.f, 0.f};
        for (int s = 0; s < 4; s++) {
            u32x4 av = *(const u32x4*)(h1 + m * 136 + s * 32 + quad * 8);
            u32x4 bv = *(const u32x4*)(m2P + (((size_t)(s * 4 + wv) * 64 + lane) << 3));
            bf16x8 a  = __builtin_bit_cast(bf16x8, av);
            bf16x8 bb = __builtin_bit_cast(bf16x8, bv);
            acc = __builtin_amdgcn_mfma_f32_16x16x32_bf16(a, bb, acc, 0, 0, 0);
        }
        int o = wv * 16 + col;
        float bb = m2_b[o];
        #pragma unroll
        for (int r = 0; r < 4; r++) {
            int pr = quad * 4 + r;
            float v = acc[r] + bb;
            v = (v < 0.0f) ? NEG * v : v;
            dout[((size_t)b * 64 + o) * NPTS + n0 + pr] = v;
            ff[pr * 68 + o] = v;
        }
    }
    __syncthreads();

    // flow = cl_w @ ff + cl_b (no activation), fp32 out
    if (t < 48) {
        int p = t & 15, oo = t >> 4;
        float a = cl_b[oo];
        #pragma unroll
        for (int i = 0; i < 64; i++)
            a += cl_w[oo * 64 + i] * ff[p * 68 + i];
        dout[(size_t)NB * 64 * NPTS + ((size_t)b * 3 + oo) * NPTS + n0 + p] = a;
    }
}

// ---------------------------------------------------------------------------
extern "C" void kernel_launch(void* const* d_in, const int* in_sizes, int n_in,
                              void* d_out, int out_size, void* d_ws, size_t ws_size,
                              hipStream_t stream) {
    const float* xyz   = (const float*)d_in[0];
    const float* feat  = (const float*)d_in[1];
    const int*   knn   = (const int*)d_in[2];
    const float* wn1_w = (const float*)d_in[3];
    const float* wn1_b = (const float*)d_in[4];
    const float* lin1w = (const float*)d_in[5];
    const float* lin1b = (const float*)d_in[6];
    const float* wn2_w = (const float*)d_in[7];
    const float* wn2_b = (const float*)d_in[8];
    const float* lin2w = (const float*)d_in[9];
    const float* lin2b = (const float*)d_in[10];
    const float* m1_w  = (const float*)d_in[11];
    const float* m1_b  = (const float*)d_in[12];
    const float* m2_w  = (const float*)d_in[13];
    const float* m2_b  = (const float*)d_in[14];
    const float* cl_w  = (const float*)d_in[15];
    const float* cl_b  = (const float*)d_in[16];
    float* out = (float*)d_out;

    char* ws = (char*)d_ws;
    const size_t BN = (size_t)NB * NPTS;
    // f2 aliases fcT1 (fcT1 dead after pc#1; pc#2 reads fcT2 only)
    u16*   fcT1 = (u16*)(ws);                      // BN*136*2 = 8,912,896
    u16*   f2   = (u16*)(ws);                      // alias (BN*128*2)
    u16*   fcT2 = (u16*)(ws + 8912896);            // 8,912,896
    float* xyzF = (float*)(ws + 17825792);         // BN*4*4 = 524,288
    u16*   lw1P = (u16*)(ws + 18350080);           // 34*8*512*2 = 278,528
    u16*   lw2P = (u16*)(ws + 18628608);           // 278,528
    u16*   m1P  = (u16*)(ws + 18907136);           // 32,768
    u16*   m2P  = (u16*)(ws + 18939904);           // 16,384 -> total 18,956,288
    // (+16B DMA overrun slack on last fcT2 row lands in xyzF region: harmless)

    (void)in_sizes; (void)n_in; (void)out_size; (void)ws_size;

    pack_fcT<<<dim3(NB * (NPTS / 64)), dim3(256), 0, stream>>>(xyz, feat, fcT1, fcT2, xyzF);
    pack_w<<<dim3(68), dim3(256), 0, stream>>>(lin1w, lw1P, 128, 1048, NSTEP, 1);
    pack_w<<<dim3(68), dim3(256), 0, stream>>>(lin2w, lw2P, 128, 1048, NSTEP, 1);
    pack_w<<<dim3(8),  dim3(256), 0, stream>>>(m1_w, m1P, 128, 128, 4, 0);
    pack_w<<<dim3(4),  dim3(256), 0, stream>>>(m2_w, m2P, 64, 128, 4, 0);

    pc_kernel<<<dim3(BN / 16), dim3(256), 0, stream>>>(
        fcT1, xyzF, knn, wn1_w, wn1_b, lw1P, lin1b, fcT2, 0);
    pc_kernel<<<dim3(BN / 16), dim3(256), 0, stream>>>(
        fcT2, xyzF, knn, wn2_w, wn2_b, lw2P, lin2b, f2, 1);

    mlp_kernel<<<dim3(BN / 16), dim3(256), 0, stream>>>(
        f2, m1P, m1_b, m2P, m2_b, cl_w, cl_b, out);
}